// Round 1
// baseline (403.375 us; speedup 1.0000x reference)
//
#include <hip/hip_runtime.h>
#include <cmath>

#define TS 32
#define HALO 5
#define ITS (TS + 2*HALO)   // 42

struct Coeffs { float k[11]; };

__global__ __launch_bounds__(256)
void ssim_level_kernel(const float* __restrict__ i1, const float* __restrict__ i2,
                       float* __restrict__ o1, float* __restrict__ o2,
                       int H, int W, int tilesX,
                       double* __restrict__ accum,   // [2][64] for this level
                       Coeffs cf)
{
    __shared__ float s1[ITS][ITS];
    __shared__ float s2[ITS][ITS];
    __shared__ float hc1[ITS][TS];
    __shared__ float hc2[ITS][TS];
    __shared__ float hc11[ITS][TS];
    __shared__ float hc22[ITS][TS];
    __shared__ float hc12[ITS][TS];
    __shared__ double red[2][4];

    const int tid = threadIdx.x;
    const int bc  = blockIdx.y;
    const int tileY = blockIdx.x / tilesX;
    const int tileX = blockIdx.x - tileY * tilesX;
    const int r0 = tileY * TS;
    const int c0 = tileX * TS;
    const float* p1 = i1 + (size_t)bc * H * W;
    const float* p2 = i2 + (size_t)bc * H * W;

    // ---- load 42x42 halo tile (zero padding at image borders) ----
    for (int idx = tid; idx < ITS*ITS; idx += 256) {
        int r = idx / ITS, c = idx - r * ITS;
        int gr = r0 + r - HALO, gc = c0 + c - HALO;
        float a = 0.f, b = 0.f;
        if (gr >= 0 && gr < H && gc >= 0 && gc < W) {
            a = p1[(size_t)gr * W + gc];
            b = p2[(size_t)gr * W + gc];
        }
        s1[r][c] = a; s2[r][c] = b;
    }
    __syncthreads();

    // ---- horizontal 11-tap pass for the 5 products ----
    for (int idx = tid; idx < ITS*TS; idx += 256) {
        int r = idx >> 5, c = idx & 31;   // TS == 32
        float h1 = 0.f, h2 = 0.f, h11 = 0.f, h22 = 0.f, h12 = 0.f;
        #pragma unroll
        for (int t = 0; t < 11; ++t) {
            float kk = cf.k[t];
            float a = s1[r][c + t], b = s2[r][c + t];
            h1  += kk * a;     h2  += kk * b;
            h11 += kk * a * a; h22 += kk * b * b; h12 += kk * a * b;
        }
        hc1[r][c] = h1; hc2[r][c] = h2;
        hc11[r][c] = h11; hc22[r][c] = h22; hc12[r][c] = h12;
    }
    __syncthreads();

    // ---- vertical 11-tap pass + SSIM math ----
    const float C1 = 1e-4f;    // 0.01^2
    const float C2 = 9e-4f;    // 0.03^2
    double ssim_acc = 0.0, cs_acc = 0.0;
    for (int idx = tid; idx < TS*TS; idx += 256) {
        int r = idx >> 5, c = idx & 31;
        float mu1 = 0.f, mu2 = 0.f, m11 = 0.f, m22 = 0.f, m12 = 0.f;
        #pragma unroll
        for (int t = 0; t < 11; ++t) {
            float kk = cf.k[t];
            mu1 += kk * hc1[r + t][c];
            mu2 += kk * hc2[r + t][c];
            m11 += kk * hc11[r + t][c];
            m22 += kk * hc22[r + t][c];
            m12 += kk * hc12[r + t][c];
        }
        float mu1s = mu1 * mu1, mu2s = mu2 * mu2, mu12 = mu1 * mu2;
        float sig1 = m11 - mu1s, sig2 = m22 - mu2s, sig12 = m12 - mu12;
        float v1 = 2.f * sig12 + C2;
        float v2 = sig1 + sig2 + C2;
        float cs = v1 / v2;
        float ssim = ((2.f * mu12 + C1) * v1) / ((mu1s + mu2s + C1) * v2);
        ssim_acc += (double)ssim;
        cs_acc   += (double)cs;
    }

    // ---- block reduction of the two sums ----
    for (int off = 32; off > 0; off >>= 1) {
        ssim_acc += __shfl_down(ssim_acc, off);
        cs_acc   += __shfl_down(cs_acc, off);
    }
    int wave = tid >> 6, lane = tid & 63;
    if (lane == 0) { red[0][wave] = ssim_acc; red[1][wave] = cs_acc; }
    __syncthreads();
    if (tid == 0) {
        double s = red[0][0] + red[0][1] + red[0][2] + red[0][3];
        double c = red[1][0] + red[1][1] + red[1][2] + red[1][3];
        int slot = (blockIdx.x + blockIdx.y) & 63;
        atomicAdd(&accum[slot], s);
        atomicAdd(&accum[64 + slot], c);
    }

    // ---- fused 2x2 avg-pool for the next level (reads raw tile from LDS) ----
    if (o1 != nullptr) {
        const int W2 = W >> 1;
        float* q1 = o1 + (size_t)bc * (H >> 1) * W2;
        float* q2 = o2 + (size_t)bc * (H >> 1) * W2;
        if (tid < 16 * 16) {
            int r = tid >> 4, c = tid & 15;
            int sr = HALO + 2 * r, sc = HALO + 2 * c;
            float a = 0.25f * (s1[sr][sc] + s1[sr][sc+1] + s1[sr+1][sc] + s1[sr+1][sc+1]);
            float b = 0.25f * (s2[sr][sc] + s2[sr][sc+1] + s2[sr+1][sc] + s2[sr+1][sc+1]);
            size_t o = (size_t)(r0/2 + r) * W2 + (c0/2 + c);
            q1[o] = a; q2[o] = b;
        }
    }
}

__global__ __launch_bounds__(64)
void finalize_kernel(const double* __restrict__ accum,  // [5][2][64]
                     float* __restrict__ out, int BC)
{
    __shared__ double sums[5][2];
    int tid = threadIdx.x;
    for (int lvl = 0; lvl < 5; ++lvl) {
        for (int m = 0; m < 2; ++m) {
            double v = accum[(lvl * 2 + m) * 64 + tid];
            for (int off = 32; off > 0; off >>= 1) v += __shfl_down(v, off);
            if (tid == 0) sums[lvl][m] = v;
        }
    }
    __syncthreads();
    if (tid == 0) {
        const double w[5] = {0.0448, 0.2856, 0.3001, 0.2363, 0.1333};
        double prod = 1.0;
        for (int lvl = 0; lvl < 5; ++lvl) {
            int hw = (512 >> lvl);
            double cnt = (double)BC * (double)hw * (double)hw;
            double mssim = sums[lvl][0] / cnt;
            double mcs   = sums[lvl][1] / cnt;
            if (lvl < 4) {
                prod *= pow(mcs, w[lvl]);
            } else {
                double p2 = pow(mssim, w[4]);
                prod *= p2 * p2 * p2 * p2;   // pow2[-1] broadcast across the 4 products
            }
        }
        out[0] = (float)(1.0 - prod);
    }
}

extern "C" void kernel_launch(void* const* d_in, const int* in_sizes, int n_in,
                              void* d_out, int out_size, void* d_ws, size_t ws_size,
                              hipStream_t stream) {
    const float* img1 = (const float*)d_in[0];
    const float* img2 = (const float*)d_in[1];
    float* out = (float*)d_out;
    char* ws = (char*)d_ws;

    const int BC = in_sizes[0] / (512 * 512);   // 96

    // ws layout: [0,5120): double accum[5][2][64]; pyramid buffers from 8192
    double* accum = (double*)ws;
    size_t off = 8192;
    float* lvl1[5] = {nullptr, nullptr, nullptr, nullptr, nullptr};
    float* lvl2[5] = {nullptr, nullptr, nullptr, nullptr, nullptr};
    for (int l = 1; l < 5; ++l) {
        size_t hw = (size_t)(512 >> l) * (512 >> l);
        lvl1[l] = (float*)(ws + off); off += (size_t)BC * hw * sizeof(float);
        lvl2[l] = (float*)(ws + off); off += (size_t)BC * hw * sizeof(float);
    }

    // zero the accumulators
    hipMemsetAsync(accum, 0, 5 * 2 * 64 * sizeof(double), stream);

    // Gaussian window, faithful to the reference's POSITIVE exponent bug
    Coeffs cf;
    {
        double kd[11], sum = 0.0;
        for (int i = 0; i < 11; ++i) { kd[i] = exp(((double)((i-5)*(i-5))) / 4.5); sum += kd[i]; }
        for (int i = 0; i < 11; ++i) cf.k[i] = (float)(kd[i] / sum);
    }

    const float* cur1 = img1;
    const float* cur2 = img2;
    for (int lvl = 0; lvl < 5; ++lvl) {
        int H = 512 >> lvl, W = H;
        int tilesX = W / TS;
        dim3 grid(tilesX * (H / TS), BC);
        float* n1 = (lvl < 4) ? lvl1[lvl + 1] : nullptr;
        float* n2 = (lvl < 4) ? lvl2[lvl + 1] : nullptr;
        ssim_level_kernel<<<grid, 256, 0, stream>>>(cur1, cur2, n1, n2, H, W, tilesX,
                                                    accum + lvl * 128, cf);
        cur1 = n1; cur2 = n2;
    }

    finalize_kernel<<<1, 64, 0, stream>>>(accum, out, BC);
}